// Round 14
// baseline (149.560 us; speedup 1.0000x reference)
//
#include <hip/hip_runtime.h>
#include <hip/hip_bf16.h>

// Adaptive_Node_Scale_GCN — MFMA v13 (4 blocks/CU: Z->8KB, per-rti A/B, 40960B LDS).
// Y[d,n] = sum_{t=0..6} W_t,d · X_{d,n} · M_{t,d}^T,  M ∈ {I, A0, A0², A1, A1², P_d, P_d²}
// v12 post-mortem: 3 blocks/CU = 105µs, every pipe <30% busy -> latency-bound; 4 blocks
// needs LDS<=40KB and regs<=128 total. v13: per-rti phaseA(D0,D1 only: AGPR 40 total)
// immediately followed by per-rti phaseB from a 2-slot wave-private 1KB Z buffer
// (Z 16K->8K); dead parity lanes broadcast-read partner addr (x*0=0) -> zero block gone.
// LDS = 32K X + 8K Z = 40960 exactly -> 4 x 40960 = 160KB pool, exact fit.

namespace {

constexpr int Kn = 128;
constexpr int En = 10;

typedef __attribute__((ext_vector_type(8))) short short8;
typedef __attribute__((ext_vector_type(4))) float f32x4;

__device__ inline unsigned short f2bf(float f) {
    unsigned x = __float_as_uint(f);
    return (unsigned short)((x + 0x7FFFu + ((x >> 16) & 1u)) >> 16);
}
__device__ inline unsigned pack2(float lo, float hi) {
    return (unsigned)f2bf(lo) | ((unsigned)f2bf(hi) << 16);
}
// packed RNE pair via builtin (emits v_cvt_pk_bf16_f32; same bits as pack2)
__device__ inline unsigned pack2b(float lo, float hi) {
    union { __hip_bfloat162 h; unsigned u; } cv;
    float2 f; f.x = lo; f.y = hi;
    cv.h = __float22bfloat162_rn(f);
    return cv.u;
}

// ---------------- precompute 1: fp32 mats ----------------
// fp32 slots: 0:A0 2:A1 4..7:P_d
__global__ __launch_bounds__(256) void build_adj(
    const float* __restrict__ supports,
    const float* __restrict__ nv1,
    const float* __restrict__ nv2,
    const float* __restrict__ impW,
    const float* __restrict__ impB,
    float* __restrict__ mats)
{
    const int tid = threadIdx.x;
    const int blk = blockIdx.x;
    if (blk < 2) {
        const float* A = supports + blk * Kn * Kn;
        float* dst = mats + (blk * 2) * Kn * Kn;   // slot 0 / slot 2
        for (int i = tid; i < Kn * Kn; i += 256) dst[i] = A[i];
        return;
    }
    const int d = blk - 2;
    __shared__ float nv1m[Kn * En];
    __shared__ float nv2s[En * Kn];
    for (int i = tid; i < Kn * En; i += 256) nv1m[i] = nv1[d * Kn * En + i];
    for (int i = tid; i < En * Kn; i += 256) nv2s[i] = nv2[d * En * Kn + i];
    __syncthreads();
    float impv[5];
    #pragma unroll
    for (int r = 0; r < 5; ++r) {
        const int idx = tid + r * 256;
        const int j = idx / En, e = idx - j * En;
        float acc = impB[j];
        for (int kk = 0; kk < Kn; ++kk)
            acc += impW[j * Kn + kk] * nv1m[kk * En + e];
        impv[r] = acc;
    }
    __syncthreads();
    #pragma unroll
    for (int r = 0; r < 5; ++r) nv1m[tid + r * 256] *= impv[r];
    __syncthreads();
    if (tid < Kn) {
        const int k = tid;
        float a[En];
        #pragma unroll
        for (int e = 0; e < En; ++e) a[e] = nv1m[k * En + e];
        float mx = 0.f;
        for (int j = 0; j < Kn; ++j) {
            float s = 0.f;
            #pragma unroll
            for (int e = 0; e < En; ++e) s += a[e] * nv2s[e * Kn + j];
            mx = fmaxf(mx, s);
        }
        float sum = 0.f;
        for (int j = 0; j < Kn; ++j) {
            float s = 0.f;
            #pragma unroll
            for (int e = 0; e < En; ++e) s += a[e] * nv2s[e * Kn + j];
            s = fmaxf(s, 0.f);
            sum += expf(s - mx);
        }
        const float inv = 1.f / sum;
        float* dst = mats + (4 + d) * Kn * Kn;
        for (int j = 0; j < Kn; ++j) {
            float s = 0.f;
            #pragma unroll
            for (int e = 0; e < En; ++e) s += a[e] * nv2s[e * Kn + j];
            s = fmaxf(s, 0.f);
            dst[k * Kn + j] = expf(s - mx) * inv;   // P[k][j], row-major
        }
    }
}

// ---------------- precompute 2: squares + bf16 stream (merged) ----------------
// wbm slots (plain row-major M[k][v] bf16):
//   0:I 1:A0 2:A0² 3:A1 4:A1² 5+2d:P_d 6+2d:P²_d
__global__ __launch_bounds__(256) void square_cvt(
    const float* __restrict__ fm, unsigned short* __restrict__ wbm)
{
    const int tid = threadIdx.x;
    if (blockIdx.x < 96) {
        __shared__ float S[Kn * Kn];
        const int m = blockIdx.x >> 4, strip = blockIdx.x & 15;
        const int src = (m == 0) ? 0 : (m == 1) ? 2 : (2 + m);     // fp32 slot
        const int dst = (m == 0) ? 2 : (m == 1) ? 4 : (2 + 2 * m); // wbm slot
        const float* s = fm + src * Kn * Kn;
        unsigned short* o = wbm + dst * Kn * Kn;
        for (int i = tid; i < Kn * Kn; i += 256) S[i] = s[i];
        __syncthreads();
        const int v = strip * 8 + (tid >> 5);
        const int k0 = (tid & 31) * 4;
        float acc0 = 0.f, acc1 = 0.f, acc2 = 0.f, acc3 = 0.f;
        for (int u0 = 0; u0 < Kn; u0 += 4) {
            const float4 av = *reinterpret_cast<const float4*>(&S[v * Kn + u0]);
            const float a[4] = {av.x, av.y, av.z, av.w};
            #pragma unroll
            for (int j = 0; j < 4; ++j) {
                const float4 m4 = *reinterpret_cast<const float4*>(&S[(u0 + j) * Kn + k0]);
                acc0 += a[j] * m4.x; acc1 += a[j] * m4.y;
                acc2 += a[j] * m4.z; acc3 += a[j] * m4.w;
            }
        }
        uint2 r;
        r.x = pack2(acc0, acc1);
        r.y = pack2(acc2, acc3);
        *reinterpret_cast<uint2*>(&o[v * Kn + k0]) = r;
    } else {
        const int s = blockIdx.x - 96;  // 0..6
        const int wslot = (s == 0) ? 0 : (s == 1) ? 1 : (s == 2) ? 3 : (5 + 2 * (s - 3));
        const int fsrc  = (s == 0) ? -1 : (s == 1) ? 0 : (s == 2) ? 2 : (4 + (s - 3));
        for (int i = tid; i < Kn * Kn; i += 256) {
            const int k = i >> 7, v = i & 127;
            const float val = (fsrc < 0) ? ((k == v) ? 1.f : 0.f) : fm[fsrc * 16384 + i];
            wbm[wslot * 16384 + i] = f2bf(val);
        }
    }
}

// ---------------- fused MFMA kernel ----------------
// block = (d, b, 8 l's, kh). LDS 40960:
//   [0,32K)  X rows (n*16+c)×256B bf16 (persistent; Y overlays at end)
//   [32K,40K) Z [wave4][slot2][j2][lr16][c16] bf16 (wave-private, 2-slot rotation)
__global__ __launch_bounds__(256, 4) void fused_mfma(
    const float* __restrict__ x,
    const unsigned short* __restrict__ wbm,
    const float* __restrict__ mlpW,   // (4,16,112)
    const float* __restrict__ mlpB,   // (4,16)
    float* __restrict__ out)
{
    __shared__ __align__(16) char lds[40960];
    const int tid = threadIdx.x;
    const int lane = tid & 63, lr = lane & 15, lg = lane >> 4;
    const int wid = tid >> 6, wr = wid >> 1, wk = wid & 1;

    const unsigned u = blockIdx.x;                 // 0..2047
    const unsigned pid = (u & 7) * 256 + (u >> 3); // XCD-chunked; kh/lt siblings same XCD
    const int kh = pid & 1;
    const int lt = (pid >> 1) & 15;
    const int b  = (pid >> 5) & 15;
    const int d  = (int)(pid >> 9);
    const int l0 = lt * 8;

    const f32x4 zero4 = {0.f, 0.f, 0.f, 0.f};
    short8 Mb[8];                                   // single M register buffer (32V)
    const unsigned short* mbase = wbm + kh * 8192 + wk * 4096 + lr * 128 + lg * 8;

    auto loadM = [&](int slot) {
        const unsigned short* mp = mbase + slot * 16384;
        #pragma unroll
        for (int j = 0; j < 2; ++j)
            #pragma unroll
            for (int ks = 0; ks < 4; ++ks)
                Mb[j * 4 + ks] =
                    *reinterpret_cast<const short8*>(mp + j * 2048 + ks * 32);
    };

    loadM(0);   // deepest in flight

    // ---- stage X: lanes = (v-pair, l-half); LDS row (n*16+c)*256B,
    //      col byte = 4*p ^ ((c&7)<<4)   (p = v/2)
    {
        const int half = tid & 1;
        const int p5 = (tid >> 1) & 31;
        #pragma unroll
        for (int i = 0; i < 8; ++i) {
            const int g = i * 4 + wid;       // 0..31
            const int c = g >> 1, pg = g & 1;
            const int p = pg * 32 + p5;      // v-pair 0..63
            const int v = p * 2;
            const float* p0 = x + (size_t)b * 1048576 + c * 65536 + d * 16384 +
                              v * 128 + l0 + half * 4;
            const float4 q0 = *reinterpret_cast<const float4*>(p0);        // v
            const float4 q1 = *reinterpret_cast<const float4*>(p0 + 128);  // v+1
            const float a0[4] = {q0.x, q0.y, q0.z, q0.w};
            const float a1[4] = {q1.x, q1.y, q1.z, q1.w};
            const int colb = (4 * p) ^ ((c & 7) << 4);
            #pragma unroll
            for (int j = 0; j < 4; ++j) {
                const int n = half * 4 + j;
                *reinterpret_cast<unsigned*>(lds + (n * 16 + c) * 256 + colb) =
                    pack2b(a0[j], a1[j]);
            }
        }
    }

    // ---- W fragments: Wf[p] holds t=2p (lanes lg<2, K 0..15) and t=2p+1
    //      (lanes lg>=2, K 16..31); t=7 slot zero.
    short8 Wf[4];
    #pragma unroll
    for (int p = 0; p < 4; ++p) {
        short8 w;
        #pragma unroll
        for (int j = 0; j < 8; ++j) {
            const int tc = lg * 8 + j, t = 2 * p + (tc >> 4), c = tc & 15;
            const float wv = (t < 7) ? mlpW[d * 1792 + lr * 112 + t * 16 + c] : 0.f;
            w[j] = (short)f2bf(wv);
        }
        Wf[p] = w;
    }

    __syncthreads();   // barrier 1: X staged (persists through the t-chain)

    // per-lane X A-frag addressing: addr = xrow + (xcol ^ ks*64) + rti*4096
    const int xrow = wr * 16384 + lr * 256;
    const int xcol = (lg * 16) ^ ((lr & 7) << 4);
    char* zb = lds + 32768 + wid * 2048;   // wave-private: 2 slots × 1KB

    f32x4 Y[4][2];
    #pragma unroll
    for (int ni = 0; ni < 4; ++ni) { Y[ni][0] = zero4; Y[ni][1] = zero4; }

    // one t: per rti {phase A (D0,D1 only) -> Z slot -> phase B}; loadM(next) at rti=3
    auto do_t = [&](int p, int parity, int nextSlot) {
        // parity-masked W: even t -> data in lanes lg<2 (K 0..15); odd -> lg>=2
        short8 Wm;
        const bool keep_lo = (parity == 0);
        #pragma unroll
        for (int j = 0; j < 8; ++j)
            Wm[j] = ((lg < 2) == keep_lo) ? Wf[p][j] : (short)0;
        #pragma unroll
        for (int rti = 0; rti < 4; ++rti) {
            f32x4 D0 = zero4, D1 = zero4;
            #pragma unroll
            for (int ks = 0; ks < 4; ++ks) {
                const short8 Xk = *reinterpret_cast<const short8*>(
                    lds + xrow + (xcol ^ (ks * 64)) + rti * 4096);
                D0 = __builtin_amdgcn_mfma_f32_16x16x32_bf16(Xk, Mb[ks], D0, 0, 0, 0);
                D1 = __builtin_amdgcn_mfma_f32_16x16x32_bf16(Xk, Mb[4 + ks], D1, 0, 0, 0);
            }
            if (rti == 3 && nextSlot >= 0) loadM(nextSlot);  // Mb free; prefetch t+1
            char* zs = zb + (rti & 1) * 1024;
            uint2 z0, z1;
            z0.x = pack2b(D0[0], D0[1]); z0.y = pack2b(D0[2], D0[3]);
            z1.x = pack2b(D1[0], D1[1]); z1.y = pack2b(D1[2], D1[3]);
            *reinterpret_cast<uint2*>(zs + lr * 32 + lg * 8) = z0;
            *reinterpret_cast<uint2*>(zs + 512 + lr * 32 + lg * 8) = z1;
            // phase B: data lanes read fresh Z; dead lanes broadcast partner addr (x*0=0)
            #pragma unroll
            for (int ktl = 0; ktl < 2; ++ktl) {
                const short8 Bfz = *reinterpret_cast<const short8*>(
                    zs + ktl * 512 + lr * 32 + (lg & 1) * 16);
                Y[rti][ktl] = __builtin_amdgcn_mfma_f32_16x16x32_bf16(
                    Wm, Bfz, Y[rti][ktl], 0, 0, 0);
            }
        }
    };

    // ---- barrier-free t-chain
    do_t(0, 0, 1);           // t0 (I)
    do_t(0, 1, 2);           // t1 (A0)
    do_t(1, 0, 3);           // t2 (A0²)
    do_t(1, 1, 4);           // t3 (A1)
    do_t(2, 0, 5 + 2 * d);   // t4 (A1²)
    do_t(2, 1, 6 + 2 * d);   // t5 (P_d)
    do_t(3, 0, -1);          // t6 (P²_d)

    __syncthreads();   // barrier 2: all waves done reading X; Y overlays X region

    // ---- Y bounce: regs -> LDS [o][k64][l8] f32 (byte ^= (k&12))
    #pragma unroll
    for (int ni = 0; ni < 4; ++ni) {
        const int l = wr * 4 + ni;
        #pragma unroll
        for (int ktl = 0; ktl < 2; ++ktl) {
            const int k = wk * 32 + ktl * 16 + lr;
            #pragma unroll
            for (int r = 0; r < 4; ++r) {
                const int o = lg * 4 + r;
                *reinterpret_cast<float*>(
                    lds + o * 2048 + k * 32 + ((l * 4) ^ (k & 12))) = Y[ni][ktl][r];
            }
        }
    }
    __syncthreads();   // barrier 3: Y chunk complete

    // ---- coalesced dwordx4 stores, lanes spanning (k, l-half): 32 lines @32B
    {
        const int half = tid & 1;
        const int klo = (tid >> 1) & 31;
        #pragma unroll
        for (int i = 0; i < 8; ++i) {
            const int g = i * 4 + wid;        // 0..31
            const int o = g >> 1, kg = g & 1;
            const int k = kg * 32 + klo;      // 0..63 local
            const int pp = (k >> 2) & 3;
            const float4 F = *reinterpret_cast<const float4*>(
                lds + o * 2048 + k * 32 + half * 16);
            float4 s1, s2;
            if (pp & 1) { s1.x = F.y; s1.y = F.x; s1.z = F.w; s1.w = F.z; }
            else        { s1 = F; }
            if (pp & 2) { s2.x = s1.z; s2.y = s1.w; s2.z = s1.x; s2.w = s1.y; }
            else        { s2 = s1; }
            const float bv = mlpB[d * 16 + o];
            s2.x += bv; s2.y += bv; s2.z += bv; s2.w += bv;
            float* gp = out + (size_t)b * 1048576 + o * 65536 + d * 16384 +
                        (kh * 64 + k) * 128 + l0 + half * 4;
            *reinterpret_cast<float4*>(gp) = s2;
        }
    }
}

}  // namespace

extern "C" void kernel_launch(void* const* d_in, const int* in_sizes, int n_in,
                              void* d_out, int out_size, void* d_ws, size_t ws_size,
                              hipStream_t stream)
{
    const float* x    = (const float*)d_in[0];
    const float* sup  = (const float*)d_in[1];
    const float* nv1  = (const float*)d_in[2];
    const float* nv2  = (const float*)d_in[3];
    const float* impW = (const float*)d_in[4];
    const float* impB = (const float*)d_in[5];
    const float* mlpW = (const float*)d_in[6];
    const float* mlpB = (const float*)d_in[7];
    float* outp = (float*)d_out;

    float* fm = (float*)d_ws;                                        // fp32 mats
    unsigned short* wbm = (unsigned short*)((char*)d_ws + 786432);   // 13 × 32KB bf16

    build_adj<<<6, 256, 0, stream>>>(sup, nv1, nv2, impW, impB, fm);
    square_cvt<<<103, 256, 0, stream>>>(fm, wbm);
    fused_mfma<<<2048, 256, 0, stream>>>(x, wbm, mlpW, mlpB, outp);
}

// Round 15
// 132.443 us; speedup vs baseline: 1.1292x; 1.1292x over previous
//
#include <hip/hip_runtime.h>
#include <hip/hip_bf16.h>

// Adaptive_Node_Scale_GCN — MFMA v14 (= v12 + Z 40B-stride conflict fix + fast build_adj).
// Y[d,n] = sum_{t=0..6} W_t,d · X_{d,n} · M_{t,d}^T,  M ∈ {I, A0, A0², A1, A1², P_d, P_d²}
// v13 post-mortem: (256,4) reg-cap spill + ILP loss -> revert to v12 base (105µs).
// v14: (1) Z row stride 32->40B (dword stride 10: 16 lr-lanes hit 16 distinct banks,
// was 4-way conflict; reads become 2x ds_read_b64, 8B-aligned), (2) build_adj P-rows
// split across 2 threads (all 256 active, 3-pass serial work halved).

namespace {

constexpr int Kn = 128;
constexpr int En = 10;

typedef __attribute__((ext_vector_type(8))) short short8;
typedef __attribute__((ext_vector_type(4))) float f32x4;

__device__ inline unsigned short f2bf(float f) {
    unsigned x = __float_as_uint(f);
    return (unsigned short)((x + 0x7FFFu + ((x >> 16) & 1u)) >> 16);
}
__device__ inline unsigned pack2(float lo, float hi) {
    return (unsigned)f2bf(lo) | ((unsigned)f2bf(hi) << 16);
}
// packed RNE pair via builtin (emits v_cvt_pk_bf16_f32; same bits as pack2)
__device__ inline unsigned pack2b(float lo, float hi) {
    union { __hip_bfloat162 h; unsigned u; } cv;
    float2 f; f.x = lo; f.y = hi;
    cv.h = __float22bfloat162_rn(f);
    return cv.u;
}

// ---------------- precompute 1: fp32 mats ----------------
// fp32 slots: 0:A0 2:A1 4..7:P_d
__global__ __launch_bounds__(256) void build_adj(
    const float* __restrict__ supports,
    const float* __restrict__ nv1,
    const float* __restrict__ nv2,
    const float* __restrict__ impW,
    const float* __restrict__ impB,
    float* __restrict__ mats)
{
    const int tid = threadIdx.x;
    const int blk = blockIdx.x;
    if (blk < 2) {
        const float* A = supports + blk * Kn * Kn;
        float* dst = mats + (blk * 2) * Kn * Kn;   // slot 0 / slot 2
        for (int i = tid; i < Kn * Kn; i += 256) dst[i] = A[i];
        return;
    }
    const int d = blk - 2;
    __shared__ float nv1m[Kn * En];
    __shared__ float nv2s[En * Kn];
    __shared__ float red[256];
    for (int i = tid; i < Kn * En; i += 256) nv1m[i] = nv1[d * Kn * En + i];
    for (int i = tid; i < En * Kn; i += 256) nv2s[i] = nv2[d * En * Kn + i];
    __syncthreads();
    float impv[5];
    #pragma unroll
    for (int r = 0; r < 5; ++r) {
        const int idx = tid + r * 256;
        const int j = idx / En, e = idx - j * En;
        float acc = impB[j];
        for (int kk = 0; kk < Kn; ++kk)
            acc += impW[j * Kn + kk] * nv1m[kk * En + e];
        impv[r] = acc;
    }
    __syncthreads();
    #pragma unroll
    for (int r = 0; r < 5; ++r) nv1m[tid + r * 256] *= impv[r];
    __syncthreads();
    // P-build: 2 threads per row k, 64 j's each; LDS pair-reduce max & sum
    {
        const int k = tid & 127, hf = tid >> 7;
        const int j0 = hf * 64;
        float a[En];
        #pragma unroll
        for (int e = 0; e < En; ++e) a[e] = nv1m[k * En + e];
        float mx = 0.f;   // relu floor
        for (int j = j0; j < j0 + 64; ++j) {
            float s = 0.f;
            #pragma unroll
            for (int e = 0; e < En; ++e) s += a[e] * nv2s[e * Kn + j];
            mx = fmaxf(mx, s);
        }
        red[tid] = mx;
        __syncthreads();
        mx = fmaxf(red[tid], red[tid ^ 128]);
        __syncthreads();
        float sum = 0.f;
        for (int j = j0; j < j0 + 64; ++j) {
            float s = 0.f;
            #pragma unroll
            for (int e = 0; e < En; ++e) s += a[e] * nv2s[e * Kn + j];
            sum += expf(fmaxf(s, 0.f) - mx);
        }
        red[tid] = sum;
        __syncthreads();
        const float inv = 1.f / (red[tid] + red[tid ^ 128]);
        float* dst = mats + (4 + d) * Kn * Kn;
        for (int j = j0; j < j0 + 64; ++j) {
            float s = 0.f;
            #pragma unroll
            for (int e = 0; e < En; ++e) s += a[e] * nv2s[e * Kn + j];
            dst[k * Kn + j] = expf(fmaxf(s, 0.f) - mx) * inv;   // P[k][j]
        }
    }
}

// ---------------- precompute 2: squares + bf16 stream (merged) ----------------
// wbm slots (plain row-major M[k][v] bf16):
//   0:I 1:A0 2:A0² 3:A1 4:A1² 5+2d:P_d 6+2d:P²_d
__global__ __launch_bounds__(256) void square_cvt(
    const float* __restrict__ fm, unsigned short* __restrict__ wbm)
{
    const int tid = threadIdx.x;
    if (blockIdx.x < 96) {
        __shared__ float S[Kn * Kn];
        const int m = blockIdx.x >> 4, strip = blockIdx.x & 15;
        const int src = (m == 0) ? 0 : (m == 1) ? 2 : (2 + m);     // fp32 slot
        const int dst = (m == 0) ? 2 : (m == 1) ? 4 : (2 + 2 * m); // wbm slot
        const float* s = fm + src * Kn * Kn;
        unsigned short* o = wbm + dst * Kn * Kn;
        for (int i = tid; i < Kn * Kn; i += 256) S[i] = s[i];
        __syncthreads();
        const int v = strip * 8 + (tid >> 5);
        const int k0 = (tid & 31) * 4;
        float acc0 = 0.f, acc1 = 0.f, acc2 = 0.f, acc3 = 0.f;
        for (int u0 = 0; u0 < Kn; u0 += 4) {
            const float4 av = *reinterpret_cast<const float4*>(&S[v * Kn + u0]);
            const float a[4] = {av.x, av.y, av.z, av.w};
            #pragma unroll
            for (int j = 0; j < 4; ++j) {
                const float4 m4 = *reinterpret_cast<const float4*>(&S[(u0 + j) * Kn + k0]);
                acc0 += a[j] * m4.x; acc1 += a[j] * m4.y;
                acc2 += a[j] * m4.z; acc3 += a[j] * m4.w;
            }
        }
        uint2 r;
        r.x = pack2(acc0, acc1);
        r.y = pack2(acc2, acc3);
        *reinterpret_cast<uint2*>(&o[v * Kn + k0]) = r;
    } else {
        const int s = blockIdx.x - 96;  // 0..6
        const int wslot = (s == 0) ? 0 : (s == 1) ? 1 : (s == 2) ? 3 : (5 + 2 * (s - 3));
        const int fsrc  = (s == 0) ? -1 : (s == 1) ? 0 : (s == 2) ? 2 : (4 + (s - 3));
        for (int i = tid; i < Kn * Kn; i += 256) {
            const int k = i >> 7, v = i & 127;
            const float val = (fsrc < 0) ? ((k == v) ? 1.f : 0.f) : fm[fsrc * 16384 + i];
            wbm[wslot * 16384 + i] = f2bf(val);
        }
    }
}

// ---------------- fused MFMA kernel ----------------
// block = (d, b, 8 l's, kh). LDS 53280:
//   [0,32K)       X rows (n*16+c)×256B bf16 (persistent; Y overlays at end)
//   [32K,52.8K)   Z [n8][kp64] rows of 40B (32B payload + 8B pad) — conflict-free
//   [53248,+32)   zero block for parity-masked phase-B dead lanes
__global__ __launch_bounds__(256, 3) void fused_mfma(
    const float* __restrict__ x,
    const unsigned short* __restrict__ wbm,
    const float* __restrict__ mlpW,   // (4,16,112)
    const float* __restrict__ mlpB,   // (4,16)
    float* __restrict__ out)
{
    __shared__ __align__(16) char lds[53280];
    const int tid = threadIdx.x;
    const int lane = tid & 63, lr = lane & 15, lg = lane >> 4;
    const int wid = tid >> 6, wr = wid >> 1, wk = wid & 1;

    const unsigned u = blockIdx.x;                 // 0..2047
    const unsigned pid = (u & 7) * 256 + (u >> 3); // XCD-chunked; kh/lt siblings same XCD
    const int kh = pid & 1;
    const int lt = (pid >> 1) & 15;
    const int b  = (pid >> 5) & 15;
    const int d  = (int)(pid >> 9);
    const int l0 = lt * 8;

    const f32x4 zero4 = {0.f, 0.f, 0.f, 0.f};
    short8 Mb[8];                                   // single M register buffer
    const unsigned short* mbase = wbm + kh * 8192 + wk * 4096 + lr * 128 + lg * 8;

    auto loadM = [&](int slot) {
        const unsigned short* mp = mbase + slot * 16384;
        #pragma unroll
        for (int j = 0; j < 2; ++j)
            #pragma unroll
            for (int ks = 0; ks < 4; ++ks)
                Mb[j * 4 + ks] =
                    *reinterpret_cast<const short8*>(mp + j * 2048 + ks * 32);
    };

    loadM(0);   // deepest in flight

    // ---- stage X: lanes = (v-pair, l-half); LDS row (n*16+c)*256B,
    //      col byte = 4*p ^ ((c&7)<<4)   (p = v/2)
    {
        const int half = tid & 1;
        const int p5 = (tid >> 1) & 31;
        #pragma unroll
        for (int i = 0; i < 8; ++i) {
            const int g = i * 4 + wid;       // 0..31
            const int c = g >> 1, pg = g & 1;
            const int p = pg * 32 + p5;      // v-pair 0..63
            const int v = p * 2;
            const float* p0 = x + (size_t)b * 1048576 + c * 65536 + d * 16384 +
                              v * 128 + l0 + half * 4;
            const float4 q0 = *reinterpret_cast<const float4*>(p0);        // v
            const float4 q1 = *reinterpret_cast<const float4*>(p0 + 128);  // v+1
            const float a0[4] = {q0.x, q0.y, q0.z, q0.w};
            const float a1[4] = {q1.x, q1.y, q1.z, q1.w};
            const int colb = (4 * p) ^ ((c & 7) << 4);
            #pragma unroll
            for (int j = 0; j < 4; ++j) {
                const int n = half * 4 + j;
                *reinterpret_cast<unsigned*>(lds + (n * 16 + c) * 256 + colb) =
                    pack2b(a0[j], a1[j]);
            }
        }
    }
    // zero block for parity-masked phase-B dead lanes
    if (tid < 8) *reinterpret_cast<unsigned*>(lds + 53248 + tid * 4) = 0u;

    // ---- W fragments: Wf[p] holds t=2p (lanes lg<2, K 0..15) and t=2p+1
    //      (lanes lg>=2, K 16..31); t=7 slot zero.
    short8 Wf[4];
    #pragma unroll
    for (int p = 0; p < 4; ++p) {
        short8 w;
        #pragma unroll
        for (int j = 0; j < 8; ++j) {
            const int tc = lg * 8 + j, t = 2 * p + (tc >> 4), c = tc & 15;
            const float wv = (t < 7) ? mlpW[d * 1792 + lr * 112 + t * 16 + c] : 0.f;
            w[j] = (short)f2bf(wv);
        }
        Wf[p] = w;
    }

    __syncthreads();   // barrier 1: X staged (persists through the t-chain)

    // per-lane X A-frag addressing: addr = xrow + (xcol ^ ks*64) + rti*4096
    const int xrow = wr * 16384 + lr * 256;
    const int xcol = (lg * 16) ^ ((lr & 7) << 4);
    char* zbase = lds + 32768;   // Z: row (n,kp) at n*2560 + kp*40

    f32x4 Y[4][2];
    #pragma unroll
    for (int ni = 0; ni < 4; ++ni) { Y[ni][0] = zero4; Y[ni][1] = zero4; }

    // phase A for one t: 16 LDS A-frag reads + 16 MFMA (8 indep chains) + Z write
    auto phaseA_Z = [&]() {
        f32x4 D[4][2];
        #pragma unroll
        for (int rti = 0; rti < 4; ++rti) { D[rti][0] = zero4; D[rti][1] = zero4; }
        #pragma unroll
        for (int ks = 0; ks < 4; ++ks) {
            const char* xaddr = lds + xrow + (xcol ^ (ks * 64));
            #pragma unroll
            for (int rti = 0; rti < 4; ++rti) {
                const short8 Xk = *reinterpret_cast<const short8*>(xaddr + rti * 4096);
                D[rti][0] = __builtin_amdgcn_mfma_f32_16x16x32_bf16(
                    Xk, Mb[ks], D[rti][0], 0, 0, 0);
                D[rti][1] = __builtin_amdgcn_mfma_f32_16x16x32_bf16(
                    Xk, Mb[4 + ks], D[rti][1], 0, 0, 0);
            }
        }
        // Z[n][kp]: 40B row, lane writes 8B at c-offset lg*8 (dword stride 10 — CF)
        #pragma unroll
        for (int rti = 0; rti < 4; ++rti) {
            #pragma unroll
            for (int j = 0; j < 2; ++j) {
                const int n = wr * 4 + rti;
                const int kp = (wk * 2 + j) * 16 + lr;
                uint2 zz;
                zz.x = pack2b(D[rti][j][0], D[rti][j][1]);
                zz.y = pack2b(D[rti][j][2], D[rti][j][3]);
                *reinterpret_cast<uint2*>(zbase + n * 2560 + kp * 40 + lg * 8) = zz;
            }
        }
    };

    // phase B for one t: parity-masked W; dead K-half reads the zero block.
    // 2x ds_read_b64 (8B-aligned 40B rows).
    auto phaseB = [&](int p, int parity) {
        short8 Wm;
        const bool keep_lo = (parity == 0);
        #pragma unroll
        for (int j = 0; j < 8; ++j)
            Wm[j] = ((lg < 2) == keep_lo) ? Wf[p][j] : (short)0;
        const bool data_lane = ((lg < 2) == keep_lo);
        #pragma unroll
        for (int ni = 0; ni < 4; ++ni) {
            const int n = wr * 4 + ni;
            #pragma unroll
            for (int ktl = 0; ktl < 2; ++ktl) {
                const int kp = wk * 32 + ktl * 16 + lr;
                const char* zp = data_lane
                    ? (zbase + n * 2560 + kp * 40 + (lg & 1) * 16)
                    : (lds + 53248 + (lg & 1) * 16);
                union { short8 s; uint2 uu[2]; } bf;
                bf.uu[0] = *reinterpret_cast<const uint2*>(zp);
                bf.uu[1] = *reinterpret_cast<const uint2*>(zp + 8);
                Y[ni][ktl] = __builtin_amdgcn_mfma_f32_16x16x32_bf16(
                    Wm, bf.s, Y[ni][ktl], 0, 0, 0);
            }
        }
    };

    // ---- barrier-free t-chain (wave-private Z; in-wave DS order is the sync)
    phaseA_Z();  loadM(1);          phaseB(0, 0);   // t0 (I)
    phaseA_Z();  loadM(2);          phaseB(0, 1);   // t1 (A0)
    phaseA_Z();  loadM(3);          phaseB(1, 0);   // t2 (A0²)
    phaseA_Z();  loadM(4);          phaseB(1, 1);   // t3 (A1)
    phaseA_Z();  loadM(5 + 2 * d);  phaseB(2, 0);   // t4 (A1²)
    phaseA_Z();  loadM(6 + 2 * d);  phaseB(2, 1);   // t5 (P_d)
    phaseA_Z();                     phaseB(3, 0);   // t6 (P²_d)

    __syncthreads();   // barrier 2: all waves done reading X; Y overlays X region

    // ---- Y bounce: regs -> LDS [o][k64][l8] f32 (byte ^= (k&12))
    #pragma unroll
    for (int ni = 0; ni < 4; ++ni) {
        const int l = wr * 4 + ni;
        #pragma unroll
        for (int ktl = 0; ktl < 2; ++ktl) {
            const int k = wk * 32 + ktl * 16 + lr;
            #pragma unroll
            for (int r = 0; r < 4; ++r) {
                const int o = lg * 4 + r;
                *reinterpret_cast<float*>(
                    lds + o * 2048 + k * 32 + ((l * 4) ^ (k & 12))) = Y[ni][ktl][r];
            }
        }
    }
    __syncthreads();   // barrier 3: Y chunk complete

    // ---- coalesced dwordx4 stores, lanes spanning (k, l-half): 32 lines @32B
    {
        const int half = tid & 1;
        const int klo = (tid >> 1) & 31;
        #pragma unroll
        for (int i = 0; i < 8; ++i) {
            const int g = i * 4 + wid;        // 0..31
            const int o = g >> 1, kg = g & 1;
            const int k = kg * 32 + klo;      // 0..63 local
            const int pp = (k >> 2) & 3;
            const float4 F = *reinterpret_cast<const float4*>(
                lds + o * 2048 + k * 32 + half * 16);
            float4 s1, s2;
            if (pp & 1) { s1.x = F.y; s1.y = F.x; s1.z = F.w; s1.w = F.z; }
            else        { s1 = F; }
            if (pp & 2) { s2.x = s1.z; s2.y = s1.w; s2.z = s1.x; s2.w = s1.y; }
            else        { s2 = s1; }
            const float bv = mlpB[d * 16 + o];
            s2.x += bv; s2.y += bv; s2.z += bv; s2.w += bv;
            float* gp = out + (size_t)b * 1048576 + o * 65536 + d * 16384 +
                        (kh * 64 + k) * 128 + l0 + half * 4;
            *reinterpret_cast<float4*>(gp) = s2;
        }
    }
}

}  // namespace

extern "C" void kernel_launch(void* const* d_in, const int* in_sizes, int n_in,
                              void* d_out, int out_size, void* d_ws, size_t ws_size,
                              hipStream_t stream)
{
    const float* x    = (const float*)d_in[0];
    const float* sup  = (const float*)d_in[1];
    const float* nv1  = (const float*)d_in[2];
    const float* nv2  = (const float*)d_in[3];
    const float* impW = (const float*)d_in[4];
    const float* impB = (const float*)d_in[5];
    const float* mlpW = (const float*)d_in[6];
    const float* mlpB = (const float*)d_in[7];
    float* outp = (float*)d_out;

    float* fm = (float*)d_ws;                                        // fp32 mats
    unsigned short* wbm = (unsigned short*)((char*)d_ws + 786432);   // 13 × 32KB bf16

    build_adj<<<6, 256, 0, stream>>>(sup, nv1, nv2, impW, impB, fm);
    square_cvt<<<103, 256, 0, stream>>>(fm, wbm);
    fused_mfma<<<2048, 256, 0, stream>>>(x, wbm, mlpW, mlpB, outp);
}

// Round 16
// 126.168 us; speedup vs baseline: 1.1854x; 1.0497x over previous
//
#include <hip/hip_runtime.h>
#include <hip/hip_bf16.h>

// Adaptive_Node_Scale_GCN — MFMA v16 (= v12 fused + 16B-granule Z swizzle + v14 precompute).
// Y[d,n] = sum_{t=0..6} W_t,d · X_{d,n} · M_{t,d}^T,  M ∈ {I, A0, A0², A1, A1², P_d, P_d²}
// v15 post-mortem: v14's 40B Z rows fixed the 4-way conflict (10.2M->4.7M) but forced
// 2x ds_read_b64 on phase B (+regression). v16: Z 32B rows with 16B-half XOR swizzle
// byte = kp*32 + ((lg*8) ^ (((kp>>2)&1)<<4)) — enumerated: b128 reads 8-deep (minimum),
// uint2 writes 4-deep (minimum). Phase B back to single ds_read_b128. Z=16KB, LDS=49216
// (v12 footprint, 3 blocks/CU). Precompute = v14's fast build_adj.

namespace {

constexpr int Kn = 128;
constexpr int En = 10;

typedef __attribute__((ext_vector_type(8))) short short8;
typedef __attribute__((ext_vector_type(4))) float f32x4;

__device__ inline unsigned short f2bf(float f) {
    unsigned x = __float_as_uint(f);
    return (unsigned short)((x + 0x7FFFu + ((x >> 16) & 1u)) >> 16);
}
__device__ inline unsigned pack2(float lo, float hi) {
    return (unsigned)f2bf(lo) | ((unsigned)f2bf(hi) << 16);
}
// packed RNE pair via builtin (emits v_cvt_pk_bf16_f32; same bits as pack2)
__device__ inline unsigned pack2b(float lo, float hi) {
    union { __hip_bfloat162 h; unsigned u; } cv;
    float2 f; f.x = lo; f.y = hi;
    cv.h = __float22bfloat162_rn(f);
    return cv.u;
}

// ---------------- precompute 1: fp32 mats ----------------
// fp32 slots: 0:A0 2:A1 4..7:P_d
__global__ __launch_bounds__(256) void build_adj(
    const float* __restrict__ supports,
    const float* __restrict__ nv1,
    const float* __restrict__ nv2,
    const float* __restrict__ impW,
    const float* __restrict__ impB,
    float* __restrict__ mats)
{
    const int tid = threadIdx.x;
    const int blk = blockIdx.x;
    if (blk < 2) {
        const float* A = supports + blk * Kn * Kn;
        float* dst = mats + (blk * 2) * Kn * Kn;   // slot 0 / slot 2
        for (int i = tid; i < Kn * Kn; i += 256) dst[i] = A[i];
        return;
    }
    const int d = blk - 2;
    __shared__ float nv1m[Kn * En];
    __shared__ float nv2s[En * Kn];
    __shared__ float red[256];
    for (int i = tid; i < Kn * En; i += 256) nv1m[i] = nv1[d * Kn * En + i];
    for (int i = tid; i < En * Kn; i += 256) nv2s[i] = nv2[d * En * Kn + i];
    __syncthreads();
    float impv[5];
    #pragma unroll
    for (int r = 0; r < 5; ++r) {
        const int idx = tid + r * 256;
        const int j = idx / En, e = idx - j * En;
        float acc = impB[j];
        for (int kk = 0; kk < Kn; ++kk)
            acc += impW[j * Kn + kk] * nv1m[kk * En + e];
        impv[r] = acc;
    }
    __syncthreads();
    #pragma unroll
    for (int r = 0; r < 5; ++r) nv1m[tid + r * 256] *= impv[r];
    __syncthreads();
    // P-build: 2 threads per row k, 64 j's each; LDS pair-reduce max & sum
    {
        const int k = tid & 127, hf = tid >> 7;
        const int j0 = hf * 64;
        float a[En];
        #pragma unroll
        for (int e = 0; e < En; ++e) a[e] = nv1m[k * En + e];
        float mx = 0.f;   // relu floor
        for (int j = j0; j < j0 + 64; ++j) {
            float s = 0.f;
            #pragma unroll
            for (int e = 0; e < En; ++e) s += a[e] * nv2s[e * Kn + j];
            mx = fmaxf(mx, s);
        }
        red[tid] = mx;
        __syncthreads();
        mx = fmaxf(red[tid], red[tid ^ 128]);
        __syncthreads();
        float sum = 0.f;
        for (int j = j0; j < j0 + 64; ++j) {
            float s = 0.f;
            #pragma unroll
            for (int e = 0; e < En; ++e) s += a[e] * nv2s[e * Kn + j];
            sum += expf(fmaxf(s, 0.f) - mx);
        }
        red[tid] = sum;
        __syncthreads();
        const float inv = 1.f / (red[tid] + red[tid ^ 128]);
        float* dst = mats + (4 + d) * Kn * Kn;
        for (int j = j0; j < j0 + 64; ++j) {
            float s = 0.f;
            #pragma unroll
            for (int e = 0; e < En; ++e) s += a[e] * nv2s[e * Kn + j];
            dst[k * Kn + j] = expf(fmaxf(s, 0.f) - mx) * inv;   // P[k][j]
        }
    }
}

// ---------------- precompute 2: squares + bf16 stream (merged) ----------------
// wbm slots (plain row-major M[k][v] bf16):
//   0:I 1:A0 2:A0² 3:A1 4:A1² 5+2d:P_d 6+2d:P²_d
__global__ __launch_bounds__(256) void square_cvt(
    const float* __restrict__ fm, unsigned short* __restrict__ wbm)
{
    const int tid = threadIdx.x;
    if (blockIdx.x < 96) {
        __shared__ float S[Kn * Kn];
        const int m = blockIdx.x >> 4, strip = blockIdx.x & 15;
        const int src = (m == 0) ? 0 : (m == 1) ? 2 : (2 + m);     // fp32 slot
        const int dst = (m == 0) ? 2 : (m == 1) ? 4 : (2 + 2 * m); // wbm slot
        const float* s = fm + src * Kn * Kn;
        unsigned short* o = wbm + dst * Kn * Kn;
        for (int i = tid; i < Kn * Kn; i += 256) S[i] = s[i];
        __syncthreads();
        const int v = strip * 8 + (tid >> 5);
        const int k0 = (tid & 31) * 4;
        float acc0 = 0.f, acc1 = 0.f, acc2 = 0.f, acc3 = 0.f;
        for (int u0 = 0; u0 < Kn; u0 += 4) {
            const float4 av = *reinterpret_cast<const float4*>(&S[v * Kn + u0]);
            const float a[4] = {av.x, av.y, av.z, av.w};
            #pragma unroll
            for (int j = 0; j < 4; ++j) {
                const float4 m4 = *reinterpret_cast<const float4*>(&S[(u0 + j) * Kn + k0]);
                acc0 += a[j] * m4.x; acc1 += a[j] * m4.y;
                acc2 += a[j] * m4.z; acc3 += a[j] * m4.w;
            }
        }
        uint2 r;
        r.x = pack2(acc0, acc1);
        r.y = pack2(acc2, acc3);
        *reinterpret_cast<uint2*>(&o[v * Kn + k0]) = r;
    } else {
        const int s = blockIdx.x - 96;  // 0..6
        const int wslot = (s == 0) ? 0 : (s == 1) ? 1 : (s == 2) ? 3 : (5 + 2 * (s - 3));
        const int fsrc  = (s == 0) ? -1 : (s == 1) ? 0 : (s == 2) ? 2 : (4 + (s - 3));
        for (int i = tid; i < Kn * Kn; i += 256) {
            const int k = i >> 7, v = i & 127;
            const float val = (fsrc < 0) ? ((k == v) ? 1.f : 0.f) : fm[fsrc * 16384 + i];
            wbm[wslot * 16384 + i] = f2bf(val);
        }
    }
}

// ---------------- fused MFMA kernel ----------------
// block = (d, b, 8 l's, kh). LDS 49216:
//   [0,32K)    X rows (n*16+c)×256B bf16 (persistent; Y overlays at end)
//   [32K,48K)  Z [n8][kp64] 32B rows, 16B-half XOR swizzle (((kp>>2)&1)<<4)
//   [48K,+32)  zero block for parity-masked phase-B dead lanes
__global__ __launch_bounds__(256, 3) void fused_mfma(
    const float* __restrict__ x,
    const unsigned short* __restrict__ wbm,
    const float* __restrict__ mlpW,   // (4,16,112)
    const float* __restrict__ mlpB,   // (4,16)
    float* __restrict__ out)
{
    __shared__ __align__(16) char lds[49216];
    const int tid = threadIdx.x;
    const int lane = tid & 63, lr = lane & 15, lg = lane >> 4;
    const int wid = tid >> 6, wr = wid >> 1, wk = wid & 1;

    const unsigned u = blockIdx.x;                 // 0..2047
    const unsigned pid = (u & 7) * 256 + (u >> 3); // XCD-chunked; kh/lt siblings same XCD
    const int kh = pid & 1;
    const int lt = (pid >> 1) & 15;
    const int b  = (pid >> 5) & 15;
    const int d  = (int)(pid >> 9);
    const int l0 = lt * 8;

    const f32x4 zero4 = {0.f, 0.f, 0.f, 0.f};
    short8 Mb[8];                                   // single M register buffer
    const unsigned short* mbase = wbm + kh * 8192 + wk * 4096 + lr * 128 + lg * 8;

    auto loadM = [&](int slot) {
        const unsigned short* mp = mbase + slot * 16384;
        #pragma unroll
        for (int j = 0; j < 2; ++j)
            #pragma unroll
            for (int ks = 0; ks < 4; ++ks)
                Mb[j * 4 + ks] =
                    *reinterpret_cast<const short8*>(mp + j * 2048 + ks * 32);
    };

    loadM(0);   // deepest in flight

    // ---- stage X: lanes = (v-pair, l-half); LDS row (n*16+c)*256B,
    //      col byte = 4*p ^ ((c&7)<<4)   (p = v/2)
    {
        const int half = tid & 1;
        const int p5 = (tid >> 1) & 31;
        #pragma unroll
        for (int i = 0; i < 8; ++i) {
            const int g = i * 4 + wid;       // 0..31
            const int c = g >> 1, pg = g & 1;
            const int p = pg * 32 + p5;      // v-pair 0..63
            const int v = p * 2;
            const float* p0 = x + (size_t)b * 1048576 + c * 65536 + d * 16384 +
                              v * 128 + l0 + half * 4;
            const float4 q0 = *reinterpret_cast<const float4*>(p0);        // v
            const float4 q1 = *reinterpret_cast<const float4*>(p0 + 128);  // v+1
            const float a0[4] = {q0.x, q0.y, q0.z, q0.w};
            const float a1[4] = {q1.x, q1.y, q1.z, q1.w};
            const int colb = (4 * p) ^ ((c & 7) << 4);
            #pragma unroll
            for (int j = 0; j < 4; ++j) {
                const int n = half * 4 + j;
                *reinterpret_cast<unsigned*>(lds + (n * 16 + c) * 256 + colb) =
                    pack2b(a0[j], a1[j]);
            }
        }
    }
    // zero block for parity-masked phase-B dead lanes
    if (tid < 8) *reinterpret_cast<unsigned*>(lds + 49152 + tid * 4) = 0u;

    // ---- W fragments: Wf[p] holds t=2p (lanes lg<2, K 0..15) and t=2p+1
    //      (lanes lg>=2, K 16..31); t=7 slot zero.
    short8 Wf[4];
    #pragma unroll
    for (int p = 0; p < 4; ++p) {
        short8 w;
        #pragma unroll
        for (int j = 0; j < 8; ++j) {
            const int tc = lg * 8 + j, t = 2 * p + (tc >> 4), c = tc & 15;
            const float wv = (t < 7) ? mlpW[d * 1792 + lr * 112 + t * 16 + c] : 0.f;
            w[j] = (short)f2bf(wv);
        }
        Wf[p] = w;
    }

    __syncthreads();   // barrier 1: X staged (persists through the t-chain)

    // per-lane X A-frag addressing: addr = xrow + (xcol ^ ks*64) + rti*4096
    const int xrow = wr * 16384 + lr * 256;
    const int xcol = (lg * 16) ^ ((lr & 7) << 4);
    char* zbase = lds + 32768;   // Z: row (n,kp) at n*2048 + kp*32, 16B-half swizzle

    f32x4 Y[4][2];
    #pragma unroll
    for (int ni = 0; ni < 4; ++ni) { Y[ni][0] = zero4; Y[ni][1] = zero4; }

    // phase A for one t: 16 LDS A-frag reads + 16 MFMA (8 indep chains) + Z write
    auto phaseA_Z = [&]() {
        f32x4 D[4][2];
        #pragma unroll
        for (int rti = 0; rti < 4; ++rti) { D[rti][0] = zero4; D[rti][1] = zero4; }
        #pragma unroll
        for (int ks = 0; ks < 4; ++ks) {
            const char* xaddr = lds + xrow + (xcol ^ (ks * 64));
            #pragma unroll
            for (int rti = 0; rti < 4; ++rti) {
                const short8 Xk = *reinterpret_cast<const short8*>(xaddr + rti * 4096);
                D[rti][0] = __builtin_amdgcn_mfma_f32_16x16x32_bf16(
                    Xk, Mb[ks], D[rti][0], 0, 0, 0);
                D[rti][1] = __builtin_amdgcn_mfma_f32_16x16x32_bf16(
                    Xk, Mb[4 + ks], D[rti][1], 0, 0, 0);
            }
        }
        // Z write: 8B per (n,kp) at (lg*8) ^ (((kp>>2)&1)<<4)  — 4-deep (minimum)
        #pragma unroll
        for (int rti = 0; rti < 4; ++rti) {
            #pragma unroll
            for (int j = 0; j < 2; ++j) {
                const int n = wr * 4 + rti;
                const int kp = (wk * 2 + j) * 16 + lr;
                uint2 zz;
                zz.x = pack2b(D[rti][j][0], D[rti][j][1]);
                zz.y = pack2b(D[rti][j][2], D[rti][j][3]);
                *reinterpret_cast<uint2*>(
                    zbase + n * 2048 + kp * 32 +
                    ((lg * 8) ^ (((kp >> 2) & 1) << 4))) = zz;
            }
        }
    };

    // phase B for one t: parity-masked W; single ds_read_b128 (16B-half swizzle);
    // dead K-half reads the zero block.
    auto phaseB = [&](int p, int parity) {
        short8 Wm;
        const bool keep_lo = (parity == 0);
        #pragma unroll
        for (int j = 0; j < 8; ++j)
            Wm[j] = ((lg < 2) == keep_lo) ? Wf[p][j] : (short)0;
        const bool data_lane = ((lg < 2) == keep_lo);
        #pragma unroll
        for (int ni = 0; ni < 4; ++ni) {
            const int n = wr * 4 + ni;
            #pragma unroll
            for (int ktl = 0; ktl < 2; ++ktl) {
                const int kp = wk * 32 + ktl * 16 + lr;
                const char* zp = data_lane
                    ? (zbase + n * 2048 + kp * 32 +
                       (((lg & 1) * 16) ^ (((kp >> 2) & 1) << 4)))
                    : (lds + 49152 + (lg & 1) * 16);
                const short8 Bfz = *reinterpret_cast<const short8*>(zp);
                Y[ni][ktl] = __builtin_amdgcn_mfma_f32_16x16x32_bf16(
                    Wm, Bfz, Y[ni][ktl], 0, 0, 0);
            }
        }
    };

    // ---- barrier-free t-chain (wave-private Z; in-wave DS order is the sync)
    phaseA_Z();  loadM(1);          phaseB(0, 0);   // t0 (I)
    phaseA_Z();  loadM(2);          phaseB(0, 1);   // t1 (A0)
    phaseA_Z();  loadM(3);          phaseB(1, 0);   // t2 (A0²)
    phaseA_Z();  loadM(4);          phaseB(1, 1);   // t3 (A1)
    phaseA_Z();  loadM(5 + 2 * d);  phaseB(2, 0);   // t4 (A1²)
    phaseA_Z();  loadM(6 + 2 * d);  phaseB(2, 1);   // t5 (P_d)
    phaseA_Z();                     phaseB(3, 0);   // t6 (P²_d)

    __syncthreads();   // barrier 2: all waves done reading X; Y overlays X region

    // ---- Y bounce: regs -> LDS [o][k64][l8] f32 (byte ^= (k&12))
    #pragma unroll
    for (int ni = 0; ni < 4; ++ni) {
        const int l = wr * 4 + ni;
        #pragma unroll
        for (int ktl = 0; ktl < 2; ++ktl) {
            const int k = wk * 32 + ktl * 16 + lr;
            #pragma unroll
            for (int r = 0; r < 4; ++r) {
                const int o = lg * 4 + r;
                *reinterpret_cast<float*>(
                    lds + o * 2048 + k * 32 + ((l * 4) ^ (k & 12))) = Y[ni][ktl][r];
            }
        }
    }
    __syncthreads();   // barrier 3: Y chunk complete

    // ---- coalesced dwordx4 stores, lanes spanning (k, l-half): 32 lines @32B
    {
        const int half = tid & 1;
        const int klo = (tid >> 1) & 31;
        #pragma unroll
        for (int i = 0; i < 8; ++i) {
            const int g = i * 4 + wid;        // 0..31
            const int o = g >> 1, kg = g & 1;
            const int k = kg * 32 + klo;      // 0..63 local
            const int pp = (k >> 2) & 3;
            const float4 F = *reinterpret_cast<const float4*>(
                lds + o * 2048 + k * 32 + half * 16);
            float4 s1, s2;
            if (pp & 1) { s1.x = F.y; s1.y = F.x; s1.z = F.w; s1.w = F.z; }
            else        { s1 = F; }
            if (pp & 2) { s2.x = s1.z; s2.y = s1.w; s2.z = s1.x; s2.w = s1.y; }
            else        { s2 = s1; }
            const float bv = mlpB[d * 16 + o];
            s2.x += bv; s2.y += bv; s2.z += bv; s2.w += bv;
            float* gp = out + (size_t)b * 1048576 + o * 65536 + d * 16384 +
                        (kh * 64 + k) * 128 + l0 + half * 4;
            *reinterpret_cast<float4*>(gp) = s2;
        }
    }
}

}  // namespace

extern "C" void kernel_launch(void* const* d_in, const int* in_sizes, int n_in,
                              void* d_out, int out_size, void* d_ws, size_t ws_size,
                              hipStream_t stream)
{
    const float* x    = (const float*)d_in[0];
    const float* sup  = (const float*)d_in[1];
    const float* nv1  = (const float*)d_in[2];
    const float* nv2  = (const float*)d_in[3];
    const float* impW = (const float*)d_in[4];
    const float* impB = (const float*)d_in[5];
    const float* mlpW = (const float*)d_in[6];
    const float* mlpB = (const float*)d_in[7];
    float* outp = (float*)d_out;

    float* fm = (float*)d_ws;                                        // fp32 mats
    unsigned short* wbm = (unsigned short*)((char*)d_ws + 786432);   // 13 × 32KB bf16

    build_adj<<<6, 256, 0, stream>>>(sup, nv1, nv2, impW, impB, fm);
    square_cvt<<<103, 256, 0, stream>>>(fm, wbm);
    fused_mfma<<<2048, 256, 0, stream>>>(x, wbm, mlpW, mlpB, outp);
}